// Round 4
// baseline (879.419 us; speedup 1.0000x reference)
//
#include <hip/hip_runtime.h>

#define NN 4096
#define DD 128
#define BB 128
#define QQ 5
#define MAXDEG 96

__device__ __forceinline__ float dot4f(float4 a, float4 b) {
    return a.x*b.x + a.y*b.y + a.z*b.z + a.w*b.w;
}

// ---------------- neighbor-list precompute (fully parallel, deterministic) ----------------
// packs (idx, q) pairs so the scan's gather does one scalar load per neighbor
__global__ void nbr_kernel(const int* __restrict__ u, const int* __restrict__ v,
                           const float* __restrict__ A, const float* __restrict__ S,
                           int* __restrict__ nbr_cnt, int2* __restrict__ nbr_pack)
{
    __shared__ int   lcnt[257];
    __shared__ int   sidx[MAXDEG];
    __shared__ float sq[MAXDEG];
    __shared__ float ssum;
    __shared__ int   stot;

    const int p    = blockIdx.x;          // 0..255 : (event i, side)
    const int i    = p >> 1;
    const int side = p & 1;
    const int other = (side == 0) ? v[i] : u[i];   // h_struct[0]=agg(v), h_struct[1]=agg(u)
    const float* Arow = A + (size_t)other * NN;
    const float* Srow = S + (size_t)other * NN;
    const int tid = threadIdx.x;          // 0..255

    const int base = tid * 16;
    int c0 = 0;
    for (int j = 0; j < 16; ++j) c0 += (Arow[base + j] > 0.0f) ? 1 : 0;
    lcnt[tid] = c0;
    __syncthreads();
    if (tid == 0) {
        int s = 0;
        for (int k = 0; k < 256; ++k) { int c = lcnt[k]; lcnt[k] = s; s += c; }
        stot = s;
    }
    __syncthreads();
    int off = lcnt[tid];
    for (int j = 0; j < 16; ++j) {
        if (Arow[base + j] > 0.0f) {
            if (off < MAXDEG) sidx[off] = base + j;
            ++off;
        }
    }
    __syncthreads();
    int cnt = stot; if (cnt > MAXDEG) cnt = MAXDEG;
    for (int jj = tid; jj < cnt; jj += 256) sq[jj] = expf(Srow[sidx[jj]]);
    __syncthreads();
    if (tid == 0) {
        float s = 0.0f;
        for (int jj = 0; jj < cnt; ++jj) s += sq[jj];
        ssum = s + 1e-7f;
    }
    __syncthreads();
    for (int jj = tid; jj < cnt; jj += 256) {
        int2 pk;
        pk.x = sidx[jj];
        pk.y = __float_as_int(sq[jj] / ssum);
        nbr_pack[p * MAXDEG + jj] = pk;
    }
    if (tid == 0) nbr_cnt[p] = cnt;
}

// ---------------- Whz init: Whz[n][d] = z0[n] . Wh[d] + bh[d] (f32) ----------------
// thread (rep = t&7, d0 = t>>3): dims d0, d0+64, k-slice [rep*16, rep*16+16)
__global__ __launch_bounds__(512) void whz_init(
    const float* __restrict__ z0, const float* __restrict__ Wh, const float* __restrict__ bh,
    float* __restrict__ Whz)
{
    const int t   = threadIdx.x;
    const int rep = t & 7;
    const int d0  = t >> 3;        // 0..63
    float4 wh0[4], wh1[4];
    #pragma unroll
    for (int m = 0; m < 4; ++m) {
        wh0[m] = *(const float4*)(Wh + (size_t)d0*DD + rep*16 + m*4);
        wh1[m] = *(const float4*)(Wh + (size_t)(d0+64)*DD + rep*16 + m*4);
    }
    const float bh0 = bh[d0], bh1 = bh[d0+64];
    const int r0 = blockIdx.x * 16;
    for (int r = r0; r < r0 + 16; ++r) {
        const float* zr = z0 + (size_t)r*DD + rep*16;
        float a0 = 0.f, a1 = 0.f;
        #pragma unroll
        for (int m = 0; m < 4; ++m) {
            float4 zz = *(const float4*)(zr + m*4);
            a0 += dot4f(zz, wh0[m]);
            a1 += dot4f(zz, wh1[m]);
        }
        a0 += __shfl_xor(a0,1); a0 += __shfl_xor(a0,2); a0 += __shfl_xor(a0,4);
        a1 += __shfl_xor(a1,1); a1 += __shfl_xor(a1,2); a1 += __shfl_xor(a1,4);
        if (rep == 0) {
            Whz[(size_t)r*DD + d0]      = a0 + bh0;
            Whz[(size_t)r*DD + d0+64]   = a1 + bh1;
        }
    }
}

// ---------------- sequential scan: 1 block, 512 threads, incremental Whz ----------------
// gather phase: wave wv: side = wv&1, slot = wv>>1; lane ln handles dims 2ln, 2ln+1
// compute phase: rep = t&7 (k-slice of 16), d0 = (t>>3)&63 (dims d0, d0+64)
__global__ __launch_bounds__(512, 1) void scan_kernel(
    const int* __restrict__ u, const int* __restrict__ v,
    const float* __restrict__ time_diff, const int* __restrict__ neg,
    float* __restrict__ z,
    const int* __restrict__ nbr_cnt, const int2* __restrict__ nbr_pack,
    const float* __restrict__ Wh,  const float* __restrict__ bh,
    const float* __restrict__ Wst, const float* __restrict__ bst,
    const float* __restrict__ Wrc, const float* __restrict__ brc,
    const float* __restrict__ Wt,  const float* __restrict__ bt,
    float* __restrict__ Whz,
    float* __restrict__ ZU, float* __restrict__ ZV,
    float* __restrict__ UNs, float* __restrict__ VNs)
{
    __shared__ float zu_s[DD], zv_s[DD];
    __shared__ float h_s[2][DD];
    __shared__ float zupd_s[2][DD];
    __shared__ float mxp[8][DD];
    __shared__ float tdi_s[8];
    __shared__ int   uv_s[2][BB];
    __shared__ int   cnt_s[2*BB];

    const int t    = threadIdx.x;
    const int wv   = t >> 6;
    const int ln   = t & 63;
    const int side = wv & 1;
    const int slot = wv >> 1;          // 0..3

    const int rep  = t & 7;
    const int d0   = (t >> 3) & 63;

    // ---- persistent register weights (k-slice of 16 per matrix per dim) ----
    float4 wh0[4], wh1[4], ws0[4], ws1[4], wr0[4], wr1[4];
    #pragma unroll
    for (int m = 0; m < 4; ++m) {
        wh0[m] = *(const float4*)(Wh  + (size_t)d0*DD       + rep*16 + m*4);
        wh1[m] = *(const float4*)(Wh  + (size_t)(d0+64)*DD  + rep*16 + m*4);
        ws0[m] = *(const float4*)(Wst + (size_t)d0*DD       + rep*16 + m*4);
        ws1[m] = *(const float4*)(Wst + (size_t)(d0+64)*DD  + rep*16 + m*4);
        wr0[m] = *(const float4*)(Wrc + (size_t)d0*DD       + rep*16 + m*4);
        wr1[m] = *(const float4*)(Wrc + (size_t)(d0+64)*DD  + rep*16 + m*4);
    }
    const float4 wt0 = *(const float4*)(Wt + (size_t)d0*4);
    const float4 wt1 = *(const float4*)(Wt + (size_t)(d0+64)*4);
    const float bh0 = bh[d0], bh1 = bh[d0+64];
    const float bs0 = bst[d0]    + brc[d0]    + bt[d0];
    const float bs1 = bst[d0+64] + brc[d0+64] + bt[d0+64];

    // stage small per-step metadata once
    if (t < BB)              { uv_s[0][t] = u[t]; uv_s[1][t] = v[t]; }
    else if (t < BB + 2*BB)  { cnt_s[t - BB] = nbr_cnt[t - BB]; }
    __syncthreads();

    for (int i = 0; i < BB; ++i) {
        const int ui = uv_s[0][i];
        const int vi = uv_s[1][i];
        const int p  = i*2 + side;
        const int cnt = cnt_s[p];

        // ---- P0a: Whz gather + masked running max (critical path, issue first) ----
        float m0 = -3.0e38f, m1 = -3.0e38f;
        for (int j = slot; j < cnt; j += 4) {
            const int2 pk = nbr_pack[(size_t)p*MAXDEG + j];   // wave-uniform scalar load
            const float qj = __int_as_float(pk.y);
            const float2 val = *(const float2*)(Whz + (size_t)pk.x*DD + ln*2);
            m0 = fmaxf(m0, qj * val.x);
            m1 = fmaxf(m1, qj * val.y);
        }
        *(float2*)&mxp[wv][ln*2] = make_float2(m0, m1);

        // ---- P0b: captures of pre-update z ----
        if (t < 32) {
            float4 val = *(const float4*)(z + (size_t)ui*DD + t*4);
            *(float4*)&zu_s[t*4] = val;
            *(float4*)(ZU + (size_t)i*DD + t*4) = val;
        } else if (t < 64) {
            const int c = t - 32;
            float4 val = *(const float4*)(z + (size_t)vi*DD + c*4);
            *(float4*)&zv_s[c*4] = val;
            *(float4*)(ZV + (size_t)i*DD + c*4) = val;
        } else if (t < 72) {
            const float sd[4] = {50.f, 7.f, 15.f, 15.f};
            tdi_s[t-64] = time_diff[i*8 + (t-64)] / sd[(t-64) & 3];
        }
        for (int e = t; e < 2*QQ*32; e += 512) {
            const int k = e >> 5, c4 = e & 31;
            const int nd = neg[i*2*QQ + k];
            float4 val = *(const float4*)(z + (size_t)nd*DD + c4*4);
            if (k < QQ) *(float4*)(VNs + ((size_t)i*QQ + k)*DD + c4*4) = val;
            else        *(float4*)(UNs + ((size_t)i*QQ + (k-QQ))*DD + c4*4) = val;
        }
        __syncthreads();   // B1

        // ---- P1: reduce partial maxes -> h_struct ----
        if (t < 256) {
            const int sd = t >> 7;       // side
            const int d  = t & 127;
            const float m = fmaxf(fmaxf(mxp[sd][d],   mxp[sd+2][d]),
                                  fmaxf(mxp[sd+4][d], mxp[sd+6][d]));
            h_s[sd][d] = (cnt_s[i*2+sd] > 0) ? 1.0f/(1.0f + expf(-m)) : 0.0f;
        }
        __syncthreads();   // B2

        // ---- P2: z_upd (weights in VGPRs) ----
        #pragma unroll
        for (int r2 = 0; r2 < 2; ++r2) {
            const float* hp = h_s[r2] + rep*16;
            const float* zp = (r2 ? zv_s : zu_s) + rep*16;
            float a0 = 0.f, a1 = 0.f;
            #pragma unroll
            for (int m = 0; m < 4; ++m) {
                float4 hh = *(const float4*)(hp + m*4);
                float4 zz = *(const float4*)(zp + m*4);
                a0 += dot4f(hh, ws0[m]) + dot4f(zz, wr0[m]);
                a1 += dot4f(hh, ws1[m]) + dot4f(zz, wr1[m]);
            }
            a0 += __shfl_xor(a0,1); a0 += __shfl_xor(a0,2); a0 += __shfl_xor(a0,4);
            a1 += __shfl_xor(a1,1); a1 += __shfl_xor(a1,2); a1 += __shfl_xor(a1,4);
            if (rep == 0) {
                const float td0 = tdi_s[r2*4+0]*wt0.x + tdi_s[r2*4+1]*wt0.y
                                + tdi_s[r2*4+2]*wt0.z + tdi_s[r2*4+3]*wt0.w;
                const float td1 = tdi_s[r2*4+0]*wt1.x + tdi_s[r2*4+1]*wt1.y
                                + tdi_s[r2*4+2]*wt1.z + tdi_s[r2*4+3]*wt1.w;
                zupd_s[r2][d0]    = 1.0f/(1.0f + expf(-(a0 + bs0 + td0)));
                zupd_s[r2][d0+64] = 1.0f/(1.0f + expf(-(a1 + bs1 + td1)));
            }
        }
        __syncthreads();   // B3

        // ---- P3: recompute Whz rows for updated nodes + scatter z ----
        #pragma unroll
        for (int r2 = 0; r2 < 2; ++r2) {
            if (ui == vi && r2 == 0) continue;    // vi's update wins (reference order)
            const int row = r2 ? vi : ui;
            const float* zp = zupd_s[r2] + rep*16;
            float a0 = 0.f, a1 = 0.f;
            #pragma unroll
            for (int m = 0; m < 4; ++m) {
                float4 zz = *(const float4*)(zp + m*4);
                a0 += dot4f(zz, wh0[m]);
                a1 += dot4f(zz, wh1[m]);
            }
            a0 += __shfl_xor(a0,1); a0 += __shfl_xor(a0,2); a0 += __shfl_xor(a0,4);
            a1 += __shfl_xor(a1,1); a1 += __shfl_xor(a1,2); a1 += __shfl_xor(a1,4);
            if (rep == 0) {
                Whz[(size_t)row*DD + d0]      = a0 + bh0;
                Whz[(size_t)row*DD + d0+64]   = a1 + bh1;
                z[(size_t)row*DD + d0]        = zupd_s[r2][d0];
                z[(size_t)row*DD + d0+64]     = zupd_s[r2][d0+64];
            }
        }
        __threadfence_block();
        __syncthreads();   // B4
    }
}

// ---------------- intensity epilogue (parallel) ----------------
__global__ void lam_kernel(const float* __restrict__ ZU, const float* __restrict__ ZV,
                           const float* __restrict__ UNs, const float* __restrict__ VNs,
                           const int* __restrict__ et,
                           const float* __restrict__ w0, const float* __restrict__ b0,
                           const float* __restrict__ w1, const float* __restrict__ b1,
                           const float* __restrict__ psi,
                           float* __restrict__ out)
{
    const int b   = blockIdx.x;            // 0..1407
    const int i   = b / 11;
    const int col = b % 11;
    const int l   = threadIdx.x;           // 0..63
    const float* xu;
    const float* xv;
    if (col == 0) { xu = ZU + (size_t)i*DD; xv = ZV + (size_t)i*DD; }
    else {
        const int k = col - 1;
        xu = (k < QQ) ? (ZU + (size_t)i*DD) : (UNs + ((size_t)i*QQ + (k-QQ))*DD);
        xv = (k < QQ) ? (VNs + ((size_t)i*QQ + k)*DD) : (ZV + (size_t)i*DD);
    }
    float g0 = xu[l]*w0[l] + xu[l+64]*w0[l+64] + xv[l]*w0[DD+l] + xv[l+64]*w0[DD+l+64];
    float g1 = xu[l]*w1[l] + xu[l+64]*w1[l+64] + xv[l]*w1[DD+l] + xv[l+64]*w1[DD+l+64];
    #pragma unroll
    for (int s = 32; s >= 1; s >>= 1) { g0 += __shfl_xor(g0, s); g1 += __shfl_xor(g1, s); }
    if (l == 0) {
        g0 += b0[0]; g1 += b1[0];
        const float p0 = psi[0], p1 = psi[1];
        float r;
        if (col == 0) {
            const int e = et[i];
            const float g = e ? g1 : g0;
            const float p = e ? p1 : p0;
            const float y = g / (p + 1e-7f);
            r = p * (fmaxf(y, 0.f) + log1pf(expf(-fabsf(y))));
        } else {
            const float y0 = g0 / (p0 + 1e-7f);
            const float y1 = g1 / (p1 + 1e-7f);
            r = p0 * (fmaxf(y0, 0.f) + log1pf(expf(-fabsf(y0))))
              + p1 * (fmaxf(y1, 0.f) + log1pf(expf(-fabsf(y1))));
        }
        out[i*11 + col] = r;
    }
}

extern "C" void kernel_launch(void* const* d_in, const int* in_sizes, int n_in,
                              void* d_out, int out_size, void* d_ws, size_t ws_size,
                              hipStream_t stream)
{
    const int*   u   = (const int*)d_in[0];
    const int*   v   = (const int*)d_in[1];
    const int*   et  = (const int*)d_in[2];
    const float* td  = (const float*)d_in[3];
    const int*   neg = (const int*)d_in[4];
    const float* z0  = (const float*)d_in[5];
    const float* A   = (const float*)d_in[6];
    const float* S   = (const float*)d_in[7];
    const float* w0  = (const float*)d_in[8];
    const float* b0  = (const float*)d_in[9];
    const float* w1  = (const float*)d_in[10];
    const float* b1  = (const float*)d_in[11];
    const float* psi = (const float*)d_in[12];
    const float* Wh  = (const float*)d_in[13];
    const float* bh  = (const float*)d_in[14];
    const float* Wst = (const float*)d_in[15];
    const float* bst = (const float*)d_in[16];
    const float* Wrc = (const float*)d_in[17];
    const float* brc = (const float*)d_in[18];
    const float* Wt  = (const float*)d_in[19];
    const float* bt  = (const float*)d_in[20];

    char* ws = (char*)d_ws;
    size_t off = 0;
    auto alloc = [&](size_t bytes) {
        void* p = ws + off;
        off = (off + bytes + 255) & ~(size_t)255;
        return p;
    };
    float* z    = (float*)alloc((size_t)NN*DD*sizeof(float));
    float* Whz  = (float*)alloc((size_t)NN*DD*sizeof(float));
    float* ZU   = (float*)alloc((size_t)BB*DD*sizeof(float));
    float* ZV   = (float*)alloc((size_t)BB*DD*sizeof(float));
    float* UNs  = (float*)alloc((size_t)BB*QQ*DD*sizeof(float));
    float* VNs  = (float*)alloc((size_t)BB*QQ*DD*sizeof(float));
    int*   ncnt = (int*)alloc((size_t)2*BB*sizeof(int));
    int2*  npk  = (int2*)alloc((size_t)2*BB*MAXDEG*sizeof(int2));

    hipMemcpyAsync(z, z0, (size_t)NN*DD*sizeof(float), hipMemcpyDeviceToDevice, stream);
    whz_init<<<NN/16, 512, 0, stream>>>(z0, Wh, bh, Whz);
    nbr_kernel<<<2*BB, 256, 0, stream>>>(u, v, A, S, ncnt, npk);
    scan_kernel<<<1, 512, 0, stream>>>(u, v, td, neg, z, ncnt, npk,
                                       Wh, bh, Wst, bst, Wrc, brc, Wt, bt,
                                       Whz, ZU, ZV, UNs, VNs);
    lam_kernel<<<BB*(1 + 2*QQ), 64, 0, stream>>>(ZU, ZV, UNs, VNs, et,
                                                 w0, b0, w1, b1, psi, (float*)d_out);
}

// Round 5
// 406.422 us; speedup vs baseline: 2.1638x; 2.1638x over previous
//
#include <hip/hip_runtime.h>

#define NN 4096
#define DD 128
#define BB 128
#define QQ 5
#define MAXDEG 96
#define SRCF 0x40000000

typedef __attribute__((ext_vector_type(4))) float f32x4;

__device__ __forceinline__ float dot4v(f32x4 a, f32x4 b) {
    return a[0]*b[0] + a[1]*b[1] + a[2]*b[2] + a[3]*b[3];
}
__device__ __forceinline__ float dot4f(float4 a, float4 b) {
    return a.x*b.x + a.y*b.y + a.z*b.z + a.w*b.w;
}

// ---------------- neighbor-list precompute (parallel) ----------------
__global__ void nbr_kernel(const int* __restrict__ u, const int* __restrict__ v,
                           const float* __restrict__ A, const float* __restrict__ S,
                           int* __restrict__ nbr_cnt, int2* __restrict__ nbr_pack)
{
    __shared__ int   lcnt[257];
    __shared__ int   sidx[MAXDEG];
    __shared__ float sq[MAXDEG];
    __shared__ float ssum;
    __shared__ int   stot;

    const int p    = blockIdx.x;          // (event i, side)
    const int i    = p >> 1;
    const int side = p & 1;
    const int other = (side == 0) ? v[i] : u[i];   // side0 = agg(v), side1 = agg(u)
    const float* Arow = A + (size_t)other * NN;
    const float* Srow = S + (size_t)other * NN;
    const int tid = threadIdx.x;          // 0..255

    const int base = tid * 16;
    int c0 = 0;
    for (int j = 0; j < 16; ++j) c0 += (Arow[base + j] > 0.0f) ? 1 : 0;
    lcnt[tid] = c0;
    __syncthreads();
    if (tid == 0) {
        int s = 0;
        for (int k = 0; k < 256; ++k) { int c = lcnt[k]; lcnt[k] = s; s += c; }
        stot = s;
    }
    __syncthreads();
    int off = lcnt[tid];
    for (int j = 0; j < 16; ++j) {
        if (Arow[base + j] > 0.0f) {
            if (off < MAXDEG) sidx[off] = base + j;
            ++off;
        }
    }
    __syncthreads();
    int cnt = stot; if (cnt > MAXDEG) cnt = MAXDEG;
    for (int jj = tid; jj < cnt; jj += 256) sq[jj] = expf(Srow[sidx[jj]]);
    __syncthreads();
    if (tid == 0) {
        float s = 0.0f;
        for (int jj = 0; jj < cnt; ++jj) s += sq[jj];
        ssum = s + 1e-7f;
    }
    __syncthreads();
    for (int jj = tid; jj < cnt; jj += 256) {
        int2 pk;
        pk.x = sidx[jj];
        pk.y = __float_as_int(sq[jj] / ssum);
        nbr_pack[p * MAXDEG + jj] = pk;
    }
    if (tid == 0) nbr_cnt[p] = cnt;
}

// ---------------- Whz0[n][d] = z0[n].Wh[d] + bh[d] (parallel) ----------------
__global__ __launch_bounds__(512) void whz_init(
    const float* __restrict__ z0, const float* __restrict__ Wh, const float* __restrict__ bh,
    float* __restrict__ Whz0)
{
    const int t   = threadIdx.x;
    const int rep = t & 7;
    const int d0  = t >> 3;        // 0..63
    float4 wh0[4], wh1[4];
    #pragma unroll
    for (int m = 0; m < 4; ++m) {
        wh0[m] = *(const float4*)(Wh + (size_t)d0*DD + rep*16 + m*4);
        wh1[m] = *(const float4*)(Wh + (size_t)(d0+64)*DD + rep*16 + m*4);
    }
    const float bh0 = bh[d0], bh1 = bh[d0+64];
    const int r0 = blockIdx.x * 16;
    for (int r = r0; r < r0 + 16; ++r) {
        const float* zr = z0 + (size_t)r*DD + rep*16;
        float a0 = 0.f, a1 = 0.f;
        #pragma unroll
        for (int m = 0; m < 4; ++m) {
            float4 zz = *(const float4*)(zr + m*4);
            a0 += dot4f(zz, wh0[m]);
            a1 += dot4f(zz, wh1[m]);
        }
        a0 += __shfl_xor(a0,1); a0 += __shfl_xor(a0,2); a0 += __shfl_xor(a0,4);
        a1 += __shfl_xor(a1,1); a1 += __shfl_xor(a1,2); a1 += __shfl_xor(a1,4);
        if (rep == 0) {
            Whz0[(size_t)r*DD + d0]    = a0 + bh0;
            Whz0[(size_t)r*DD + d0+64] = a1 + bh1;
        }
    }
}

// ---------------- last-update sources for u,v,neg rows (parallel) ----------------
__global__ void src_kernel(const int* __restrict__ u, const int* __restrict__ v,
                           const int* __restrict__ neg,
                           int* __restrict__ zsrc, int* __restrict__ negsrc)
{
    const int i = blockIdx.x;
    const int k = threadIdx.x;       // 0..63, use 0..11
    if (k >= 2 + 2*QQ) return;
    const int n = (k == 0) ? u[i] : (k == 1) ? v[i] : neg[i*2*QQ + (k-2)];
    int s = n;
    for (int j = i-1; j >= 0; --j) {
        if (v[j] == n) { s = SRCF | (j*2 + 1); break; }
        if (u[j] == n) { s = SRCF | (j*2 + 0); break; }
    }
    if (k < 2) zsrc[i*2 + k] = s;
    else       negsrc[i*2*QQ + (k-2)] = s;
}

// ---------------- static-max + correction lists per (i,side) (parallel) ----------------
__global__ void prep_kernel(const int* __restrict__ u, const int* __restrict__ v,
                            const int* __restrict__ nbr_cnt, const int2* __restrict__ nbr_pack,
                            const float* __restrict__ Whz0,
                            float* __restrict__ maxpre, int* __restrict__ ncorr,
                            int* __restrict__ corr_src, float* __restrict__ corr_q)
{
    __shared__ int   su[BB], sv[BB];
    __shared__ int   sidx[MAXDEG];
    __shared__ float sq[MAXDEG];
    __shared__ unsigned char cflag[MAXDEG];
    __shared__ int ccnt;

    const int p   = blockIdx.x;
    const int i   = p >> 1;
    const int tid = threadIdx.x;     // 0..127
    if (tid < BB) { su[tid] = u[tid]; sv[tid] = v[tid]; }
    if (tid == 0) ccnt = 0;
    const int cnt = nbr_cnt[p];
    for (int jj = tid; jj < cnt; jj += 128) {
        int2 pk = nbr_pack[p*MAXDEG + jj];
        sidx[jj] = pk.x; sq[jj] = __int_as_float(pk.y);
    }
    __syncthreads();
    for (int jj = tid; jj < cnt; jj += 128) {
        const int r = sidx[jj];
        int fs = -1;
        for (int j = i-1; j >= 0; --j) {
            if (sv[j] == r) { fs = j*2 + 1; break; }
            if (su[j] == r) { fs = j*2 + 0; break; }
        }
        if (fs >= 0) {
            const int pos = atomicAdd(&ccnt, 1);   // order-free: folded with max (commutative)
            corr_src[p*MAXDEG + pos] = fs;
            corr_q[p*MAXDEG + pos]   = sq[jj];
            cflag[jj] = 1;
        } else cflag[jj] = 0;
    }
    __syncthreads();
    const int d = tid;               // 0..127
    float m = -3.0e38f;
    for (int jj = 0; jj < cnt; ++jj)
        if (!cflag[jj]) m = fmaxf(m, sq[jj] * Whz0[(size_t)sidx[jj]*DD + d]);
    maxpre[(size_t)p*DD + d] = m;
    if (tid == 0) ncorr[p] = ccnt;
}

// ---------------- sequential scan: 1 block, 512 threads, log-structured ----------------
// gather: wave0/4 = h sides, wave1/5 = zu/zv, wave2 = tdi
// compute: rep = t&7 (k-slice 16), d0 = (t>>3)&63 (dims d0, d0+64)
__global__ __launch_bounds__(512, 1) void scan_kernel(
    const float* __restrict__ z0, const float* __restrict__ time_diff,
    const int* __restrict__ nbr_cnt, const int* __restrict__ ncorr,
    const int* __restrict__ corr_src, const float* __restrict__ corr_q,
    const float* __restrict__ maxpre, const int* __restrict__ zsrc,
    const float* __restrict__ Wh,  const float* __restrict__ bh,
    const float* __restrict__ Wst, const float* __restrict__ bst,
    const float* __restrict__ Wrc, const float* __restrict__ brc,
    const float* __restrict__ Wt,  const float* __restrict__ bt,
    float* __restrict__ zlog, float* __restrict__ Whzlog)
{
    __shared__ float h_s[2][DD];
    __shared__ float zu_s[DD], zv_s[DD];
    __shared__ float zupd_s[2][DD];
    __shared__ float tdi_s[8];
    __shared__ int   cnt_s[2*BB], ncorr_s[2*BB], zsrc_s[2*BB];

    const int t   = threadIdx.x;
    const int wv  = t >> 6;
    const int ln  = t & 63;
    const int rep = t & 7;
    const int d0  = (t >> 3) & 63;

    // ---- persistent register weights: k-slice 16, dims d0 & d0+64 ----
    f32x4 wh0[4], wh1[4], ws0[4], ws1[4], wr0[4], wr1[4];
    #pragma unroll
    for (int m = 0; m < 4; ++m) {
        wh0[m] = *(const f32x4*)(Wh  + (size_t)d0*DD      + rep*16 + m*4);
        wh1[m] = *(const f32x4*)(Wh  + (size_t)(d0+64)*DD + rep*16 + m*4);
        ws0[m] = *(const f32x4*)(Wst + (size_t)d0*DD      + rep*16 + m*4);
        ws1[m] = *(const f32x4*)(Wst + (size_t)(d0+64)*DD + rep*16 + m*4);
        wr0[m] = *(const f32x4*)(Wrc + (size_t)d0*DD      + rep*16 + m*4);
        wr1[m] = *(const f32x4*)(Wrc + (size_t)(d0+64)*DD + rep*16 + m*4);
    }
    f32x4 wt0 = *(const f32x4*)(Wt + (size_t)d0*4);
    f32x4 wt1 = *(const f32x4*)(Wt + (size_t)(d0+64)*4);
    const float bh0 = bh[d0], bh1 = bh[d0+64];
    const float bs0 = bst[d0]    + brc[d0]    + bt[d0];
    const float bs1 = bst[d0+64] + brc[d0+64] + bt[d0+64];

    if (t < 256)      { cnt_s[t] = nbr_cnt[t]; ncorr_s[t] = ncorr[t]; }
    else              { zsrc_s[t-256] = zsrc[t-256]; }
    __syncthreads();

    for (int i = 0; i < BB; ++i) {
        // force the 26 weight vectors to stay register-resident across the loop
        asm volatile("" : "+v"(wh0[0]),"+v"(wh0[1]),"+v"(wh0[2]),"+v"(wh0[3]),
                          "+v"(wh1[0]),"+v"(wh1[1]),"+v"(wh1[2]),"+v"(wh1[3]));
        asm volatile("" : "+v"(ws0[0]),"+v"(ws0[1]),"+v"(ws0[2]),"+v"(ws0[3]),
                          "+v"(ws1[0]),"+v"(ws1[1]),"+v"(ws1[2]),"+v"(ws1[3]));
        asm volatile("" : "+v"(wr0[0]),"+v"(wr0[1]),"+v"(wr0[2]),"+v"(wr0[3]),
                          "+v"(wr1[0]),"+v"(wr1[1]),"+v"(wr1[2]),"+v"(wr1[3]),
                          "+v"(wt0),"+v"(wt1));

        // ---- P0: h gather (maxpre + corrections), zu/zv, tdi ----
        if (wv == 0 || wv == 4) {
            const int side = wv >> 2;
            const int p = i*2 + side;
            float2 m = *(const float2*)&maxpre[(size_t)p*DD + ln*2];
            const int nc = ncorr_s[p];
            for (int c = 0; c < nc; ++c) {
                const int   src = corr_src[p*MAXDEG + c];
                const float qc  = corr_q[p*MAXDEG + c];
                const float2 val = *(const float2*)&Whzlog[(size_t)src*DD + ln*2];
                m.x = fmaxf(m.x, qc * val.x);
                m.y = fmaxf(m.y, qc * val.y);
            }
            if (cnt_s[p] > 0) {
                h_s[side][ln*2]   = 1.0f/(1.0f + expf(-m.x));
                h_s[side][ln*2+1] = 1.0f/(1.0f + expf(-m.y));
            } else {
                h_s[side][ln*2] = 0.0f; h_s[side][ln*2+1] = 0.0f;
            }
        } else if (wv == 1 || wv == 5) {
            const int r2 = wv >> 2;
            const int s = zsrc_s[i*2 + r2];
            const float* src = (s & SRCF) ? (zlog + (size_t)(s & 0xFFFF)*DD)
                                          : (z0   + (size_t)s*DD);
            const float2 val = *(const float2*)&src[ln*2];
            float* dst = r2 ? zv_s : zu_s;
            *(float2*)&dst[ln*2] = val;
        } else if (wv == 2 && ln < 8) {
            const float sd[4] = {50.f, 7.f, 15.f, 15.f};
            tdi_s[ln] = time_diff[i*8 + ln] / sd[ln & 3];
        }
        __syncthreads();   // B1

        // ---- P1: z_upd ----
        #pragma unroll
        for (int r2 = 0; r2 < 2; ++r2) {
            const float* hp = h_s[r2] + rep*16;
            const float* zp = (r2 ? zv_s : zu_s) + rep*16;
            float a0 = 0.f, a1 = 0.f;
            #pragma unroll
            for (int m = 0; m < 4; ++m) {
                f32x4 hh = *(const f32x4*)(hp + m*4);
                f32x4 zz = *(const f32x4*)(zp + m*4);
                a0 += dot4v(hh, ws0[m]) + dot4v(zz, wr0[m]);
                a1 += dot4v(hh, ws1[m]) + dot4v(zz, wr1[m]);
            }
            a0 += __shfl_xor(a0,1); a0 += __shfl_xor(a0,2); a0 += __shfl_xor(a0,4);
            a1 += __shfl_xor(a1,1); a1 += __shfl_xor(a1,2); a1 += __shfl_xor(a1,4);
            if (rep == 0) {
                const float td0 = tdi_s[r2*4+0]*wt0[0] + tdi_s[r2*4+1]*wt0[1]
                                + tdi_s[r2*4+2]*wt0[2] + tdi_s[r2*4+3]*wt0[3];
                const float td1 = tdi_s[r2*4+0]*wt1[0] + tdi_s[r2*4+1]*wt1[1]
                                + tdi_s[r2*4+2]*wt1[2] + tdi_s[r2*4+3]*wt1[3];
                zupd_s[r2][d0]    = 1.0f/(1.0f + expf(-(a0 + bs0 + td0)));
                zupd_s[r2][d0+64] = 1.0f/(1.0f + expf(-(a1 + bs1 + td1)));
            }
        }
        __syncthreads();   // B2

        // ---- P2: Whz rows of the two updates -> logs ----
        #pragma unroll
        for (int r2 = 0; r2 < 2; ++r2) {
            const float* zp = zupd_s[r2] + rep*16;
            float a0 = 0.f, a1 = 0.f;
            #pragma unroll
            for (int m = 0; m < 4; ++m) {
                f32x4 zz = *(const f32x4*)(zp + m*4);
                a0 += dot4v(zz, wh0[m]);
                a1 += dot4v(zz, wh1[m]);
            }
            a0 += __shfl_xor(a0,1); a0 += __shfl_xor(a0,2); a0 += __shfl_xor(a0,4);
            a1 += __shfl_xor(a1,1); a1 += __shfl_xor(a1,2); a1 += __shfl_xor(a1,4);
            if (rep == 0) {
                const size_t row = (size_t)(i*2 + r2) * DD;
                Whzlog[row + d0]      = a0 + bh0;
                Whzlog[row + d0 + 64] = a1 + bh1;
                zlog[row + d0]        = zupd_s[r2][d0];
                zlog[row + d0 + 64]   = zupd_s[r2][d0+64];
            }
        }
        __threadfence_block();
        __syncthreads();   // B3
    }
}

// ---------------- intensity epilogue (parallel, reads via src indices) ----------------
__global__ void lam_kernel(const float* __restrict__ z0, const float* __restrict__ zlog,
                           const int* __restrict__ zsrc, const int* __restrict__ negsrc,
                           const int* __restrict__ et,
                           const float* __restrict__ w0, const float* __restrict__ b0,
                           const float* __restrict__ w1, const float* __restrict__ b1,
                           const float* __restrict__ psi,
                           float* __restrict__ out)
{
    const int b   = blockIdx.x;            // 0..1407
    const int i   = b / 11;
    const int col = b % 11;
    const int l   = threadIdx.x;           // 0..63

    auto rp = [&](int s) -> const float* {
        return (s & SRCF) ? (zlog + (size_t)(s & 0xFFFF)*DD) : (z0 + (size_t)s*DD);
    };
    const float* xu;
    const float* xv;
    if (col == 0) { xu = rp(zsrc[i*2]); xv = rp(zsrc[i*2+1]); }
    else {
        const int k = col - 1;
        xu = (k < QQ) ? rp(zsrc[i*2])            : rp(negsrc[i*2*QQ + k]);
        xv = (k < QQ) ? rp(negsrc[i*2*QQ + k])   : rp(zsrc[i*2+1]);
    }
    float g0 = xu[l]*w0[l] + xu[l+64]*w0[l+64] + xv[l]*w0[DD+l] + xv[l+64]*w0[DD+l+64];
    float g1 = xu[l]*w1[l] + xu[l+64]*w1[l+64] + xv[l]*w1[DD+l] + xv[l+64]*w1[DD+l+64];
    #pragma unroll
    for (int s = 32; s >= 1; s >>= 1) { g0 += __shfl_xor(g0, s); g1 += __shfl_xor(g1, s); }
    if (l == 0) {
        g0 += b0[0]; g1 += b1[0];
        const float p0 = psi[0], p1 = psi[1];
        float r;
        if (col == 0) {
            const int e = et[i];
            const float g = e ? g1 : g0;
            const float p = e ? p1 : p0;
            const float y = g / (p + 1e-7f);
            r = p * (fmaxf(y, 0.f) + log1pf(expf(-fabsf(y))));
        } else {
            const float y0 = g0 / (p0 + 1e-7f);
            const float y1 = g1 / (p1 + 1e-7f);
            r = p0 * (fmaxf(y0, 0.f) + log1pf(expf(-fabsf(y0))))
              + p1 * (fmaxf(y1, 0.f) + log1pf(expf(-fabsf(y1))));
        }
        out[i*11 + col] = r;
    }
}

extern "C" void kernel_launch(void* const* d_in, const int* in_sizes, int n_in,
                              void* d_out, int out_size, void* d_ws, size_t ws_size,
                              hipStream_t stream)
{
    const int*   u   = (const int*)d_in[0];
    const int*   v   = (const int*)d_in[1];
    const int*   et  = (const int*)d_in[2];
    const float* td  = (const float*)d_in[3];
    const int*   neg = (const int*)d_in[4];
    const float* z0  = (const float*)d_in[5];
    const float* A   = (const float*)d_in[6];
    const float* S   = (const float*)d_in[7];
    const float* w0  = (const float*)d_in[8];
    const float* b0  = (const float*)d_in[9];
    const float* w1  = (const float*)d_in[10];
    const float* b1  = (const float*)d_in[11];
    const float* psi = (const float*)d_in[12];
    const float* Wh  = (const float*)d_in[13];
    const float* bh  = (const float*)d_in[14];
    const float* Wst = (const float*)d_in[15];
    const float* bst = (const float*)d_in[16];
    const float* Wrc = (const float*)d_in[17];
    const float* brc = (const float*)d_in[18];
    const float* Wt  = (const float*)d_in[19];
    const float* bt  = (const float*)d_in[20];

    char* ws = (char*)d_ws;
    size_t off = 0;
    auto alloc = [&](size_t bytes) {
        void* p = ws + off;
        off = (off + bytes + 255) & ~(size_t)255;
        return p;
    };
    float* Whz0   = (float*)alloc((size_t)NN*DD*sizeof(float));
    float* maxpre = (float*)alloc((size_t)2*BB*DD*sizeof(float));
    float* zlog   = (float*)alloc((size_t)2*BB*DD*sizeof(float));
    float* Whzlog = (float*)alloc((size_t)2*BB*DD*sizeof(float));
    int*   ncnt   = (int*)alloc((size_t)2*BB*sizeof(int));
    int*   ncorr  = (int*)alloc((size_t)2*BB*sizeof(int));
    int*   csrc   = (int*)alloc((size_t)2*BB*MAXDEG*sizeof(int));
    float* cq     = (float*)alloc((size_t)2*BB*MAXDEG*sizeof(float));
    int*   zsrc   = (int*)alloc((size_t)2*BB*sizeof(int));
    int*   negsrc = (int*)alloc((size_t)BB*2*QQ*sizeof(int));
    int2*  npk    = (int2*)alloc((size_t)2*BB*MAXDEG*sizeof(int2));

    whz_init<<<NN/16, 512, 0, stream>>>(z0, Wh, bh, Whz0);
    nbr_kernel<<<2*BB, 256, 0, stream>>>(u, v, A, S, ncnt, npk);
    src_kernel<<<BB, 64, 0, stream>>>(u, v, neg, zsrc, negsrc);
    prep_kernel<<<2*BB, 128, 0, stream>>>(u, v, ncnt, npk, Whz0, maxpre, ncorr, csrc, cq);
    scan_kernel<<<1, 512, 0, stream>>>(z0, td, ncnt, ncorr, csrc, cq, maxpre, zsrc,
                                       Wh, bh, Wst, bst, Wrc, brc, Wt, bt,
                                       zlog, Whzlog);
    lam_kernel<<<BB*(1 + 2*QQ), 64, 0, stream>>>(z0, zlog, zsrc, negsrc, et,
                                                 w0, b0, w1, b1, psi, (float*)d_out);
}